// Round 1
// baseline (609.560 us; speedup 1.0000x reference)
//
#include <hip/hip_runtime.h>

#define IN_SZ 8192
#define OUT_SZ 8192

// sigmoid(2.0)
#define SIG_TAU 0.8807970779778823f

// ---------------------------------------------------------------------------
// Kernel 1: zero the I accumulator region (d_out[0:OUT_SZ]) — d_out is
// poisoned 0xAA before every call, so we must clear it ourselves.
// ---------------------------------------------------------------------------
__global__ void zeroI_kernel(float* __restrict__ I) {
    int j = blockIdx.x * blockDim.x + threadIdx.x;
    if (j < OUT_SZ) I[j] = 0.0f;
}

// ---------------------------------------------------------------------------
// Kernel 2: split-K gemv partials.  I[j] = sum_i x[i] * W[i*OUT_SZ + j]
// grid = (OUT_SZ/1024 col tiles, IN_SZ/ROWS row chunks), block = 256.
// Each thread owns 4 consecutive columns (float4), loops ROWS rows, then
// atomicAdds its 4 partial sums into the accumulator.
// W reads: 1024 consecutive floats per block per row -> fully coalesced.
// ---------------------------------------------------------------------------
template <int ROWS>
__global__ void gemv_partial_kernel(const float* __restrict__ x,
                                    const float* __restrict__ W,
                                    float* __restrict__ Iacc) {
    __shared__ float xs[ROWS];
    const int tid  = threadIdx.x;
    const int col0 = blockIdx.x * 1024 + tid * 4;
    const int row0 = blockIdx.y * ROWS;

    if (tid < ROWS) xs[tid] = x[row0 + tid];
    __syncthreads();

    float4 acc = make_float4(0.f, 0.f, 0.f, 0.f);
    const float* wp = W + (size_t)row0 * OUT_SZ + col0;
#pragma unroll 8
    for (int r = 0; r < ROWS; ++r) {
        float4 w = *(const float4*)wp;
        float xi = xs[r];
        acc.x += xi * w.x;
        acc.y += xi * w.y;
        acc.z += xi * w.z;
        acc.w += xi * w.w;
        wp += OUT_SZ;
    }
    atomicAdd(&Iacc[col0 + 0], acc.x);
    atomicAdd(&Iacc[col0 + 1], acc.y);
    atomicAdd(&Iacc[col0 + 2], acc.z);
    atomicAdd(&Iacc[col0 + 3], acc.w);
}

// ---------------------------------------------------------------------------
// Kernel 3: finalize cell update.
//   I        = Iacc[j]  (currently stored at d_out[j])
//   u_new    = sig_tau*u[j] + I
//   s        = (u_new - 1 > 0) ? 1 : 0
//   u_out[j] = u_new - s * (V_TH - V_RESET) = u_new - s
//   s is written at d_out[OUT_SZ + IN_SZ*OUT_SZ + j]
// ---------------------------------------------------------------------------
__global__ void finalize_kernel(const float* __restrict__ u,
                                float* __restrict__ out) {
    int j = blockIdx.x * blockDim.x + threadIdx.x;
    if (j >= OUT_SZ) return;
    float I     = out[j];
    float u_new = SIG_TAU * u[j] + I;
    float s     = (u_new - 1.0f > 0.0f) ? 1.0f : 0.0f;
    out[j] = u_new - s;
    out[(size_t)OUT_SZ + (size_t)IN_SZ * OUT_SZ + j] = s;
}

// ---------------------------------------------------------------------------
// Kernel 4: eligibility-trace update (the big elementwise pass).
//   J_new[i][j] = sig_tau * J[i][j] + x[i]
// One block per row; 256 threads x float4 x 8 iters = 8192 cols.
// ---------------------------------------------------------------------------
__global__ void jup_kernel(const float* __restrict__ x,
                           const float* __restrict__ J,
                           float* __restrict__ Jout) {
    const int row = blockIdx.x;
    const float xi = x[row];
    const float4* jp = (const float4*)(J + (size_t)row * OUT_SZ);
    float4* op = (float4*)(Jout + (size_t)row * OUT_SZ);
    const int tid = threadIdx.x;
#pragma unroll
    for (int c = 0; c < OUT_SZ / 4 / 256; ++c) {
        float4 v = jp[c * 256 + tid];
        v.x = SIG_TAU * v.x + xi;
        v.y = SIG_TAU * v.y + xi;
        v.z = SIG_TAU * v.z + xi;
        v.w = SIG_TAU * v.w + xi;
        op[c * 256 + tid] = v;
    }
}

extern "C" void kernel_launch(void* const* d_in, const int* in_sizes, int n_in,
                              void* d_out, int out_size, void* d_ws, size_t ws_size,
                              hipStream_t stream) {
    const float* x = (const float*)d_in[0];   // [IN_SZ]
    const float* u = (const float*)d_in[1];   // [OUT_SZ]
    const float* J = (const float*)d_in[2];   // [IN_SZ, OUT_SZ]
    const float* W = (const float*)d_in[3];   // [IN_SZ, OUT_SZ]
    float* out = (float*)d_out;

    // Independent big elementwise pass first (it dominates runtime).
    jup_kernel<<<IN_SZ, 256, 0, stream>>>(x, J, out + OUT_SZ);

    // gemv: zero accumulator, partial sums with atomics, then finalize.
    zeroI_kernel<<<(OUT_SZ + 255) / 256, 256, 0, stream>>>(out);
    gemv_partial_kernel<64><<<dim3(OUT_SZ / 1024, IN_SZ / 64), 256, 0, stream>>>(x, W, out);
    finalize_kernel<<<(OUT_SZ + 255) / 256, 256, 0, stream>>>(u, out);
}